// Round 6
// baseline (323.142 us; speedup 1.0000x reference)
//
#include <hip/hip_runtime.h>
#include <hip/hip_bf16.h>

typedef __bf16 bf16_t;
typedef __attribute__((ext_vector_type(8))) __bf16 bf16x8;
typedef __attribute__((ext_vector_type(4))) float f32x4;
typedef __attribute__((ext_vector_type(2))) float f32x2;

// physical XCD id (HW_REG_XCC_ID = hwreg 20 on gfx940+/gfx950, HW-verified)
__device__ inline int xcc_id() {
    int x;
    asm volatile("s_getreg_b32 %0, hwreg(20, 0, 32)" : "=s"(x));
    return x & 7;
}
// workgroup-scope atomic -> global_atomic_add WITHOUT sc1: executes in the
// local XCD's L2. Safe here because each replica plane is only ever touched
// by blocks on that XCD (single TCC serializes the RMWs).
__device__ inline int l2AtomicAdd(int* p, int v) {
    return __hip_atomic_fetch_add(p, v, __ATOMIC_RELAXED, __HIP_MEMORY_SCOPE_WORKGROUP);
}

// ------- pack B[K,N] f32 -> bf16 MFMA fragments ---------------------------
__device__ inline void packB_one(const float* __restrict__ B, bf16_t* __restrict__ Bp,
                                 int N, int idx) {
    int j    = idx & 7;
    int lane = (idx >> 3) & 63;
    int st   = idx >> 9;
    int nt   = N >> 4;
    int s = st / nt, t = st - s * nt;
    int k = s * 32 + (lane >> 4) * 8 + j;
    int n = t * 16 + (lane & 15);
    Bp[idx] = (bf16_t)B[(size_t)k * N + n];
}

// fp8 e4m3 decode: 8 fp8 (uint2) -> fma into a[0..8) with weight w
__device__ inline void fma8_fp8(uint2 u, float w, float* a) {
    f32x2 p;
    p = __builtin_amdgcn_cvt_pk_f32_fp8(u.x, false); a[0] += p[0] * w; a[1] += p[1] * w;
    p = __builtin_amdgcn_cvt_pk_f32_fp8(u.x, true);  a[2] += p[0] * w; a[3] += p[1] * w;
    p = __builtin_amdgcn_cvt_pk_f32_fp8(u.y, false); a[4] += p[0] * w; a[5] += p[1] * w;
    p = __builtin_amdgcn_cvt_pk_f32_fp8(u.y, true);  a[6] += p[0] * w; a[7] += p[1] * w;
}

// ------- prep: pack W1/W2 fragments + zero deg8 (8 XCD replicas) ----------
__global__ __launch_bounds__(256) void k_prep(
        const float* __restrict__ W1, bf16_t* __restrict__ Bp1,
        const float* __restrict__ W2, bf16_t* __restrict__ Bp2,
        int* __restrict__ deg8, int n8) {
    int b = blockIdx.x, t = threadIdx.x;
    const int PACKB = (32768 + 4096) / 256;   // 144
    if (b < PACKB) {
        int idx = b * 256 + t;
        if (idx < 32768) packB_one(W1, Bp1, 128, idx);
        else             packB_one(W2, Bp2, 32, idx - 32768);
        return;
    }
    int i = ((b - PACKB) * 256 + t) * 4;
    if (i < n8) {
        if (i + 4 <= n8) *(int4*)(deg8 + i) = make_int4(0, 0, 0, 0);
        else for (int j = 0; i + j < n8; ++j) deg8[i + j] = 0;
    }
}

// ------- fused front-end: XCD-local deg/rank atomics ∥ f32-A GEMM1 --------
// blocks [0, DEGB):      deg histogram into this XCD's replica plane;
//                        rank[e] = (xcd<<28) | local_rank  (L2-rate atomics)
// blocks [DEGB, +GEMMB): XW1 = fp8_e4m3(feat @ W1), MFMA 16x16x32
template <int KSTEPS, int NTILES>
__global__ __launch_bounds__(256) void k_front(
        const float* __restrict__ feat, const bf16_t* __restrict__ Bp1,
        unsigned char* __restrict__ XW1, int M,
        const int* __restrict__ dst, int* __restrict__ deg8,
        int* __restrict__ rank, int Nn, int E, int DEGB) {
    int b = blockIdx.x, t = threadIdx.x;
    if (b < DEGB) {
        int x = xcc_id();
        int* degx = deg8 + (size_t)x * Nn;
        int tag = x << 28;
        int i = b * 1024 + t * 4;
        if (i + 4 <= E) {
            int4 v = *(const int4*)(dst + i);
            int4 r;
            r.x = l2AtomicAdd(&degx[v.x], 1) | tag;
            r.y = l2AtomicAdd(&degx[v.y], 1) | tag;
            r.z = l2AtomicAdd(&degx[v.z], 1) | tag;
            r.w = l2AtomicAdd(&degx[v.w], 1) | tag;
            *(int4*)(rank + i) = r;
        } else {
            for (int j = 0; j < 4; ++j)
                if (i + j < E) rank[i + j] = l2AtomicAdd(&degx[dst[i + j]], 1) | tag;
        }
        return;
    }
    b -= DEGB;
    {
        int wave = (b * 256 + t) >> 6;
        if (wave * 16 >= M) return;
        int lane = t & 63;
        int r16 = lane & 15, quad = lane >> 4;
        const int K = KSTEPS * 32, N = NTILES * 16;
        f32x4 acc[NTILES] = {};
        const float* arow = feat + (size_t)(wave * 16 + r16) * K + quad * 8;
#pragma unroll
        for (int s = 0; s < KSTEPS; ++s) {
            const float* ap = arow + s * 32;
            bf16x8 a;
#pragma unroll
            for (int j = 0; j < 8; ++j) a[j] = (bf16_t)ap[j];
            const bf16_t* bp = Bp1 + ((size_t)(s * NTILES) * 64 + lane) * 8;
#pragma unroll
            for (int tt = 0; tt < NTILES; ++tt) {
                bf16x8 bb = *(const bf16x8*)(bp + tt * 512);
                acc[tt] = __builtin_amdgcn_mfma_f32_16x16x32_bf16(a, bb, acc[tt], 0, 0, 0);
            }
        }
#pragma unroll
        for (int tt = 0; tt < NTILES; ++tt)
#pragma unroll
            for (int r = 0; r < 4; ++r) {
                int pk = __builtin_amdgcn_cvt_pk_fp8_f32(acc[tt][r], acc[tt][r], 0, false);
                XW1[(size_t)(wave * 16 + quad * 4 + r) * N + tt * 16 + r16] =
                    (unsigned char)pk;
            }
    }
}

// ------- dinv + replica-merge + per-XCD offsets + scan phase 1 ------------
// degTot[i] = sum_x deg8[x][i];  off[x][i] = sum_{x'<x} deg8[x'][i]
__global__ __launch_bounds__(256) void k_dinv_scan1(
        const int* __restrict__ deg8, int* __restrict__ degTot,
        int* __restrict__ off, float* __restrict__ dinv,
        int* __restrict__ bsum, int n) {
    __shared__ int red[256];
    int b = blockIdx.x, t = threadIdx.x;
    int base = b * 1024 + t * 4;
    int s = 0;
#pragma unroll
    for (int j = 0; j < 4; ++j) {
        int i = base + j;
        if (i < n) {
            int run = 0;
#pragma unroll
            for (int x = 0; x < 8; ++x) {
                int v = deg8[(size_t)x * n + i];
                off[(size_t)x * n + i] = run;
                run += v;
            }
            degTot[i] = run;
            s += run;
            dinv[i] = rsqrtf((float)(run + 1));
        }
    }
    red[t] = s;
    __syncthreads();
    for (int d = 128; d > 0; d >>= 1) {
        if (t < d) red[t] += red[t + d];
        __syncthreads();
    }
    if (t == 0) bsum[b] = red[0];
}

// fused scan2+scan3: every block redundantly scans bsum (<=256 entries) in
// LDS for its own exclusive offset, then block-local scan -> rowPtr.
__global__ __launch_bounds__(256) void k_scan3f(const int* __restrict__ degTot,
                                                const int* __restrict__ bsum, int nb,
                                                int* __restrict__ rowPtr, int n) {
    __shared__ int red[256];
    __shared__ int boff[256];
    int b = blockIdx.x, t = threadIdx.x;
    int base = b * 1024 + t * 4;
    int v[4]; int s = 0;
#pragma unroll
    for (int j = 0; j < 4; ++j) { int i = base + j; v[j] = (i < n) ? degTot[i] : 0; s += v[j]; }
    red[t] = s;
    boff[t] = (t < nb) ? bsum[t] : 0;
    __syncthreads();
    for (int d = 1; d < 256; d <<= 1) {   // Hillis-Steele inclusive, both arrays
        int u  = (t >= d) ? red[t - d]  : 0;
        int u2 = (t >= d) ? boff[t - d] : 0;
        __syncthreads();
        red[t] += u;
        boff[t] += u2;
        __syncthreads();
    }
    int blockOff = (b == 0) ? 0 : boff[b - 1];          // exclusive block offset
    if (b == 0 && t == 0) rowPtr[n] = boff[nb - 1];     // total = E
    int run = blockOff + red[t] - s;
#pragma unroll
    for (int j = 0; j < 4; ++j) {
        int i = base + j;
        if (i < n) { rowPtr[i] = run; run += v[j]; }
    }
}

// ------- atomic-free scatter: pos = rowPtr[d] + off[xcd][d] + local_rank --
__global__ __launch_bounds__(256) void k_scatter(
        const int* __restrict__ src, const int* __restrict__ dst,
        const int* __restrict__ rank, const int* __restrict__ rowPtr,
        const int* __restrict__ off, const float* __restrict__ dinv,
        int2* __restrict__ edata, int Nn, int E) {
    int i = (blockIdx.x * 256 + threadIdx.x) * 4;
    if (i + 4 <= E) {
        int4 s4 = *(const int4*)(src + i);
        int4 d4 = *(const int4*)(dst + i);
        int4 r4 = *(const int4*)(rank + i);
        int p0 = rowPtr[d4.x] + off[(size_t)(((unsigned)r4.x) >> 28) * Nn + d4.x] + (r4.x & 0x0FFFFFFF);
        int p1 = rowPtr[d4.y] + off[(size_t)(((unsigned)r4.y) >> 28) * Nn + d4.y] + (r4.y & 0x0FFFFFFF);
        int p2 = rowPtr[d4.z] + off[(size_t)(((unsigned)r4.z) >> 28) * Nn + d4.z] + (r4.z & 0x0FFFFFFF);
        int p3 = rowPtr[d4.w] + off[(size_t)(((unsigned)r4.w) >> 28) * Nn + d4.w] + (r4.w & 0x0FFFFFFF);
        int2 e0; e0.x = s4.x; e0.y = __float_as_int(dinv[s4.x] * dinv[d4.x]);
        int2 e1; e1.x = s4.y; e1.y = __float_as_int(dinv[s4.y] * dinv[d4.y]);
        int2 e2; e2.x = s4.z; e2.y = __float_as_int(dinv[s4.z] * dinv[d4.z]);
        int2 e3; e3.x = s4.w; e3.y = __float_as_int(dinv[s4.w] * dinv[d4.w]);
        edata[p0] = e0; edata[p1] = e1; edata[p2] = e2; edata[p3] = e3;
    } else {
        for (int j = 0; j < 4; ++j) {
            int e = i + j;
            if (e >= E) break;
            int s = src[e], d = dst[e];
            int r = rank[e];
            int2 p; p.x = s; p.y = __float_as_int(dinv[s] * dinv[d]);
            edata[rowPtr[d] + off[(size_t)(((unsigned)r) >> 28) * Nn + d] + (r & 0x0FFFFFFF)] = p;
        }
    }
}

// ------- packed-A GEMM (layer 2, bf16 out) --------------------------------
template <int KSTEPS, int NTILES>
__global__ __launch_bounds__(256) void k_gemm_p(
        const bf16_t* __restrict__ Ap, const bf16_t* __restrict__ Bp,
        bf16_t* __restrict__ C, int M) {
    int wave = (blockIdx.x * blockDim.x + threadIdx.x) >> 6;
    if (wave * 16 >= M) return;
    int lane = threadIdx.x & 63;
    int r16 = lane & 15, quad = lane >> 4;
    const int N = NTILES * 16;
    f32x4 acc[NTILES] = {};
    const bf16_t* apb = Ap + (size_t)wave * (KSTEPS * 512) + lane * 8;
#pragma unroll
    for (int s = 0; s < KSTEPS; ++s) {
        bf16x8 a = *(const bf16x8*)(apb + s * 512);
        const bf16_t* bp = Bp + ((size_t)(s * NTILES) * 64 + lane) * 8;
#pragma unroll
        for (int t = 0; t < NTILES; ++t) {
            bf16x8 b = *(const bf16x8*)(bp + t * 512);
            acc[t] = __builtin_amdgcn_mfma_f32_16x16x32_bf16(a, b, acc[t], 0, 0, 0);
        }
    }
#pragma unroll
    for (int t = 0; t < NTILES; ++t)
#pragma unroll
        for (int r = 0; r < 4; ++r)
            C[(size_t)(wave * 16 + quad * 4 + r) * N + t * 16 + r16] = (bf16_t)acc[t][r];
}

// ------- layer-1 aggregate over fp8 XW1 rows (128B), packed Hp out --------
__global__ __launch_bounds__(256) void k_agg1(
        const int* __restrict__ rowPtr, const int2* __restrict__ edata,
        const unsigned char* __restrict__ XW1, const float* __restrict__ dinv,
        const float* __restrict__ b1, bf16_t* __restrict__ Hp, int n) {
    int wave = (blockIdx.x * blockDim.x + threadIdx.x) >> 6;
    if (wave >= n) return;
    int lane = threadIdx.x & 63;
    int fl = (lane & 15) << 3;   // 8 features (bytes, 1B/feat)
    int h  = lane >> 4;          // parity stream 0..3
    int r0 = rowPtr[wave], r1 = rowPtr[wave + 1];
    // self-term preload (independent, hides under the gather loop)
    float d = dinv[wave], d2 = d * d;
    uint2 us = *(const uint2*)(XW1 + (size_t)wave * 128 + fl);
    float a0[8] = {}, a1[8] = {};
    int k = r0 + h;
    for (; k + 4 < r1; k += 8) {          // 2 independent gathers in flight
        int2 e0 = edata[k], e1 = edata[k + 4];
        float w0 = __int_as_float(e0.y), w1 = __int_as_float(e1.y);
        uint2 u0 = *(const uint2*)(XW1 + (size_t)e0.x * 128 + fl);
        uint2 u1 = *(const uint2*)(XW1 + (size_t)e1.x * 128 + fl);
        fma8_fp8(u0, w0, a0);
        fma8_fp8(u1, w1, a1);
    }
    if (k < r1) {
        int2 e0 = edata[k];
        float w0 = __int_as_float(e0.y);
        uint2 u0 = *(const uint2*)(XW1 + (size_t)e0.x * 128 + fl);
        fma8_fp8(u0, w0, a0);
    }
#pragma unroll
    for (int j = 0; j < 8; ++j) {        // convergent reduction over 4 streams
        a0[j] += a1[j];
        a0[j] += __shfl_xor(a0[j], 16);
        a0[j] += __shfl_xor(a0[j], 32);
    }
    if (h == 0) {
        fma8_fp8(us, d2, a0);            // self term
        bf16x8 hv;
#pragma unroll
        for (int j = 0; j < 8; ++j) {
            float v = a0[j] + b1[fl + j];
            hv[j] = (bf16_t)fmaxf(v, 0.f);
        }
        int q = lane & 15;
        size_t off2 = (((size_t)(wave >> 4) * 4 + (q >> 2)) * 64
                       + (wave & 15) + 16 * (q & 3)) * 8;
        *(bf16x8*)(Hp + off2) = hv;
    }
}

// ------- layer-2 aggregate + log_softmax (bf16 XW2) -----------------------
__global__ __launch_bounds__(256) void k_agg2(
        const int* __restrict__ rowPtr, const int2* __restrict__ edata,
        const bf16_t* __restrict__ XW2, const float* __restrict__ dinv,
        const float* __restrict__ b2, float* __restrict__ out, int n) {
    int wave = (blockIdx.x * blockDim.x + threadIdx.x) >> 6;
    if (wave >= n) return;
    int lane = threadIdx.x & 63;
    int g = lane & 15;           // class pair: {2g, 2g+1}
    int h = lane >> 4;           // stream 0..3
    int r0 = rowPtr[wave], r1 = rowPtr[wave + 1];
    // self-term preload
    float d = dinv[wave], d2 = d * d;
    unsigned ps = *(const unsigned*)(XW2 + ((size_t)wave << 5) + 2 * g);
    float2 bb = *(const float2*)(b2 + 2 * g);
    float a00 = 0.f, a01 = 0.f, a10 = 0.f, a11 = 0.f;
    int k = r0 + h;
    for (; k + 4 < r1; k += 8) {
        int2 e0 = edata[k], e1 = edata[k + 4];
        float w0 = __int_as_float(e0.y), w1 = __int_as_float(e1.y);
        unsigned p0 = *(const unsigned*)(XW2 + ((size_t)e0.x << 5) + 2 * g);
        unsigned p1 = *(const unsigned*)(XW2 + ((size_t)e1.x << 5) + 2 * g);
        a00 += __int_as_float(p0 << 16) * w0;
        a01 += __int_as_float(p0 & 0xffff0000u) * w0;
        a10 += __int_as_float(p1 << 16) * w1;
        a11 += __int_as_float(p1 & 0xffff0000u) * w1;
    }
    if (k < r1) {
        int2 e0 = edata[k];
        float w0 = __int_as_float(e0.y);
        unsigned p0 = *(const unsigned*)(XW2 + ((size_t)e0.x << 5) + 2 * g);
        a00 += __int_as_float(p0 << 16) * w0;
        a01 += __int_as_float(p0 & 0xffff0000u) * w0;
    }
    float v0 = a00 + a10, v1 = a01 + a11;
    v0 += __shfl_xor(v0, 16); v0 += __shfl_xor(v0, 32);   // combine 4 streams
    v1 += __shfl_xor(v1, 16); v1 += __shfl_xor(v1, 32);
    v0 += __int_as_float(ps << 16) * d2 + bb.x;
    v1 += __int_as_float(ps & 0xffff0000u) * d2 + bb.y;
    float mx = fmaxf(v0, v1);
#pragma unroll
    for (int m = 8; m >= 1; m >>= 1) mx = fmaxf(mx, __shfl_xor(mx, m));
    float s = __expf(v0 - mx) + __expf(v1 - mx);
#pragma unroll
    for (int m = 8; m >= 1; m >>= 1) s += __shfl_xor(s, m);
    if (h == 0) {
        float ls = __logf(s);
        float2 o; o.x = v0 - mx - ls; o.y = v1 - mx - ls;
        *(float2*)(out + ((size_t)wave << 5) + 2 * g) = o;
    }
}

extern "C" void kernel_launch(void* const* d_in, const int* in_sizes, int n_in,
                              void* d_out, int out_size, void* d_ws, size_t ws_size,
                              hipStream_t stream) {
    const float* feat = (const float*)d_in[0];
    const int*   eidx = (const int*)d_in[1];
    const float* W1   = (const float*)d_in[2];
    const float* b1   = (const float*)d_in[3];
    const float* W2   = (const float*)d_in[4];
    const float* b2   = (const float*)d_in[5];
    float* out = (float*)d_out;

    const int FIN = 256, HID = 128, NCLS = 32;
    const int N = in_sizes[0] / FIN;   // 100000
    const int E = in_sizes[1] / 2;     // 800000
    const int* src = eidx;
    const int* dst = eidx + E;

    // workspace carve-up (256B aligned)
    char* ws = (char*)d_ws;
    size_t o = 0;
    auto alloc = [&](size_t bytes) -> void* {
        void* p = ws + o;
        o = (o + bytes + 255) & ~(size_t)255;
        return p;
    };
    int*    deg8   = (int*)   alloc((size_t)8 * N * 4);     // 3.2 MB XCD replicas
    int*    offA   = (int*)   alloc((size_t)8 * N * 4);     // 3.2 MB per-XCD offsets
    int*    degTot = (int*)   alloc((size_t)N * 4);
    int*    rank   = (int*)   alloc((size_t)E * 4);         // 3.2 MB packed ranks
    float*  dinv   = (float*) alloc((size_t)N * 4);
    int*    rowPtr = (int*)   alloc((size_t)(N + 1) * 4);
    int*    bsum   = (int*)   alloc(256 * 4);
    bf16_t* Bp1    = (bf16_t*)alloc((size_t)(FIN / 32) * (HID / 16) * 512 * 2);
    bf16_t* Bp2    = (bf16_t*)alloc((size_t)(HID / 32) * (NCLS / 16) * 512 * 2);
    int2*   edata  = (int2*)  alloc((size_t)E * 8);         // 6.4 MB
    unsigned char* XW1 = (unsigned char*)alloc((size_t)N * HID);  // 12.8 MB fp8
    bf16_t* Hp     = (bf16_t*)alloc((size_t)N * HID * 2);   // 25.6 MB packed H
    bf16_t* XW2    = (bf16_t*)XW1;  // alias: XW1 dead after k_agg1 (6.4 <= 12.8 MB)

    const int T = 256;
    const int NB = (N + 1023) >> 10;                 // 98 scan blocks (<=256)
    const int DEGB  = (E + 1023) / 1024;             // 782 (4 edges/thread)
    const int GEMMB = (((N + 15) / 16) * 64 + T - 1) / T;   // 1563
    const int PACKB = (32768 + 4096) / 256;          // 144
    const int ZB    = (8 * N / 4 + T - 1) / T;       // 782 deg8-zero blocks

    k_prep      <<<PACKB + ZB, T, 0, stream>>>(W1, Bp1, W2, Bp2, deg8, 8 * N);
    k_front<8, 8><<<DEGB + GEMMB, T, 0, stream>>>(
        feat, Bp1, XW1, N, dst, deg8, rank, N, E, DEGB);
    k_dinv_scan1<<<NB, T, 0, stream>>>(deg8, degTot, offA, dinv, bsum, N);
    k_scan3f    <<<NB, T, 0, stream>>>(degTot, bsum, NB, rowPtr, N);
    k_scatter   <<<(E + 1023) / 1024, T, 0, stream>>>(
        src, dst, rank, rowPtr, offA, dinv, edata, N, E);
    k_agg1<<<(N * 64 + T - 1) / T, T, 0, stream>>>(rowPtr, edata, XW1, dinv, b1, Hp, N);
    // layer 2: XW2 = bf16(Hp @ W2), A packed
    {
        int waves = (N + 15) / 16;
        k_gemm_p<4, 2><<<(waves * 64 + T - 1) / T, T, 0, stream>>>(Hp, Bp2, XW2, N);
    }
    k_agg2<<<(N * 64 + T - 1) / T, T, 0, stream>>>(rowPtr, edata, XW2, dinv, b2, out, N);
}

// Round 7
// 311.556 us; speedup vs baseline: 1.0372x; 1.0372x over previous
//
#include <hip/hip_runtime.h>
#include <hip/hip_bf16.h>

typedef __bf16 bf16_t;
typedef __attribute__((ext_vector_type(8))) __bf16 bf16x8;
typedef __attribute__((ext_vector_type(4))) float f32x4;
typedef __attribute__((ext_vector_type(2))) float f32x2;

#define RANGES 32
#define SLICES 16

// ------- pack B[K,N] f32 -> bf16 MFMA fragments ---------------------------
__device__ inline void packB_one(const float* __restrict__ B, bf16_t* __restrict__ Bp,
                                 int N, int idx) {
    int j    = idx & 7;
    int lane = (idx >> 3) & 63;
    int st   = idx >> 9;
    int nt   = N >> 4;
    int s = st / nt, t = st - s * nt;
    int k = s * 32 + (lane >> 4) * 8 + j;
    int n = t * 16 + (lane & 15);
    Bp[idx] = (bf16_t)B[(size_t)k * N + n];
}

// fp8 e4m3 decode: 8 fp8 (uint2) -> fma into a[0..8) with weight w
__device__ inline void fma8_fp8(uint2 u, float w, float* a) {
    f32x2 p;
    p = __builtin_amdgcn_cvt_pk_f32_fp8(u.x, false); a[0] += p[0] * w; a[1] += p[1] * w;
    p = __builtin_amdgcn_cvt_pk_f32_fp8(u.x, true);  a[2] += p[0] * w; a[3] += p[1] * w;
    p = __builtin_amdgcn_cvt_pk_f32_fp8(u.y, false); a[4] += p[0] * w; a[5] += p[1] * w;
    p = __builtin_amdgcn_cvt_pk_f32_fp8(u.y, true);  a[6] += p[0] * w; a[7] += p[1] * w;
}

// ------- prep: pack W1/W2 fragments (tiny, must precede front's GEMM) -----
__global__ __launch_bounds__(256) void k_prep(
        const float* __restrict__ W1, bf16_t* __restrict__ Bp1,
        const float* __restrict__ W2, bf16_t* __restrict__ Bp2) {
    int idx = blockIdx.x * 256 + threadIdx.x;
    if (idx < 32768) packB_one(W1, Bp1, 128, idx);
    else             packB_one(W2, Bp2, 32, idx - 32768);
}

// ------- fused front-end: LDS-histogram deg/rank (ZERO global atomics) ----
//         ∥ f32-A GEMM1 (fp8 out)
// blocks [0, DEGB=512): (range r, slice s): LDS histogram over 3125-node
//   range; rank[e] = (s<<24) | lds_local_rank; plane writeback to degS[s].
//   Every (slice,node) cell written => no global zeroing needed.
// blocks [DEGB, +GEMMB): XW1 = fp8_e4m3(feat @ W1), MFMA 16x16x32
template <int KSTEPS, int NTILES>
__global__ __launch_bounds__(256) void k_front(
        const float* __restrict__ feat, const bf16_t* __restrict__ Bp1,
        unsigned char* __restrict__ XW1, int M,
        const int* __restrict__ dst, int* __restrict__ degS,
        int* __restrict__ rank, int Nn, int E, int DEGB) {
    int b = blockIdx.x, t = threadIdx.x;
    if (b < DEGB) {
        __shared__ int hist[3200];
        const int CHUNK = (Nn + RANGES - 1) / RANGES;   // 3125
        int r = b >> 4, s = b & (SLICES - 1);
        int base = r * CHUNK;
        int top  = min(base + CHUNK, Nn);
        int len  = top - base;
        for (int i = t; i < len; i += 256) hist[i] = 0;
        __syncthreads();
        int tag = s << 24;
        int sliceLen = ((E + (SLICES * 4 - 1)) / (SLICES * 4)) * 4;  // 4-aligned
        int e0 = s * sliceLen;
        int e1 = min(e0 + sliceLen, E);
        for (int i = e0 + t * 4; i < e1; i += 1024) {
            if (i + 4 <= e1) {
                int4 v = *(const int4*)(dst + i);
                if (v.x >= base && v.x < top) rank[i]     = tag | atomicAdd(&hist[v.x - base], 1);
                if (v.y >= base && v.y < top) rank[i + 1] = tag | atomicAdd(&hist[v.y - base], 1);
                if (v.z >= base && v.z < top) rank[i + 2] = tag | atomicAdd(&hist[v.z - base], 1);
                if (v.w >= base && v.w < top) rank[i + 3] = tag | atomicAdd(&hist[v.w - base], 1);
            } else {
                for (int j = 0; j < 4 && i + j < e1; ++j) {
                    int d = dst[i + j];
                    if (d >= base && d < top) rank[i + j] = tag | atomicAdd(&hist[d - base], 1);
                }
            }
        }
        __syncthreads();
        int* dplane = degS + (size_t)s * Nn + base;
        for (int i = t; i < len; i += 256) dplane[i] = hist[i];
        return;
    }
    b -= DEGB;
    {
        int wave = (b * 256 + t) >> 6;
        if (wave * 16 >= M) return;
        int lane = t & 63;
        int r16 = lane & 15, quad = lane >> 4;
        const int K = KSTEPS * 32, N = NTILES * 16;
        f32x4 acc[NTILES] = {};
        const float* arow = feat + (size_t)(wave * 16 + r16) * K + quad * 8;
#pragma unroll
        for (int s = 0; s < KSTEPS; ++s) {
            const float* ap = arow + s * 32;
            bf16x8 a;
#pragma unroll
            for (int j = 0; j < 8; ++j) a[j] = (bf16_t)ap[j];
            const bf16_t* bp = Bp1 + ((size_t)(s * NTILES) * 64 + lane) * 8;
#pragma unroll
            for (int tt = 0; tt < NTILES; ++tt) {
                bf16x8 bb = *(const bf16x8*)(bp + tt * 512);
                acc[tt] = __builtin_amdgcn_mfma_f32_16x16x32_bf16(a, bb, acc[tt], 0, 0, 0);
            }
        }
#pragma unroll
        for (int tt = 0; tt < NTILES; ++tt)
#pragma unroll
            for (int r = 0; r < 4; ++r) {
                int pk = __builtin_amdgcn_cvt_pk_fp8_f32(acc[tt][r], acc[tt][r], 0, false);
                XW1[(size_t)(wave * 16 + quad * 4 + r) * N + tt * 16 + r16] =
                    (unsigned char)pk;
            }
    }
}

// ------- dinv + slice-plane merge + per-slice offsets + scan phase 1 ------
// degTot[i] = sum_s degS[s][i];  off[s][i] = sum_{s'<s} degS[s'][i]
__global__ __launch_bounds__(256) void k_dinv_scan1(
        const int* __restrict__ degS, int* __restrict__ degTot,
        int* __restrict__ off, float* __restrict__ dinv,
        int* __restrict__ bsum, int n) {
    __shared__ int red[256];
    int b = blockIdx.x, t = threadIdx.x;
    int base = b * 1024 + t * 4;
    int s = 0;
#pragma unroll
    for (int j = 0; j < 4; ++j) {
        int i = base + j;
        if (i < n) {
            int run = 0;
#pragma unroll
            for (int x = 0; x < SLICES; ++x) {
                int v = degS[(size_t)x * n + i];
                off[(size_t)x * n + i] = run;
                run += v;
            }
            degTot[i] = run;
            s += run;
            dinv[i] = rsqrtf((float)(run + 1));
        }
    }
    red[t] = s;
    __syncthreads();
    for (int d = 128; d > 0; d >>= 1) {
        if (t < d) red[t] += red[t + d];
        __syncthreads();
    }
    if (t == 0) bsum[b] = red[0];
}

// fused scan2+scan3: every block redundantly scans bsum (<=256 entries) in
// LDS for its own exclusive offset, then block-local scan -> rowPtr.
__global__ __launch_bounds__(256) void k_scan3f(const int* __restrict__ degTot,
                                                const int* __restrict__ bsum, int nb,
                                                int* __restrict__ rowPtr, int n) {
    __shared__ int red[256];
    __shared__ int boff[256];
    int b = blockIdx.x, t = threadIdx.x;
    int base = b * 1024 + t * 4;
    int v[4]; int s = 0;
#pragma unroll
    for (int j = 0; j < 4; ++j) { int i = base + j; v[j] = (i < n) ? degTot[i] : 0; s += v[j]; }
    red[t] = s;
    boff[t] = (t < nb) ? bsum[t] : 0;
    __syncthreads();
    for (int d = 1; d < 256; d <<= 1) {   // Hillis-Steele inclusive, both arrays
        int u  = (t >= d) ? red[t - d]  : 0;
        int u2 = (t >= d) ? boff[t - d] : 0;
        __syncthreads();
        red[t] += u;
        boff[t] += u2;
        __syncthreads();
    }
    int blockOff = (b == 0) ? 0 : boff[b - 1];          // exclusive block offset
    if (b == 0 && t == 0) rowPtr[n] = boff[nb - 1];     // total = E
    int run = blockOff + red[t] - s;
#pragma unroll
    for (int j = 0; j < 4; ++j) {
        int i = base + j;
        if (i < n) { rowPtr[i] = run; run += v[j]; }
    }
}

// ------- atomic-free scatter: pos = rowPtr[d] + off[slice][d] + lrank -----
__global__ __launch_bounds__(256) void k_scatter(
        const int* __restrict__ src, const int* __restrict__ dst,
        const int* __restrict__ rank, const int* __restrict__ rowPtr,
        const int* __restrict__ off, const float* __restrict__ dinv,
        int2* __restrict__ edata, int Nn, int E) {
    int i = (blockIdx.x * 256 + threadIdx.x) * 4;
    if (i + 4 <= E) {
        int4 s4 = *(const int4*)(src + i);
        int4 d4 = *(const int4*)(dst + i);
        int4 r4 = *(const int4*)(rank + i);
        int p0 = rowPtr[d4.x] + off[(size_t)(((unsigned)r4.x) >> 24) * Nn + d4.x] + (r4.x & 0x00FFFFFF);
        int p1 = rowPtr[d4.y] + off[(size_t)(((unsigned)r4.y) >> 24) * Nn + d4.y] + (r4.y & 0x00FFFFFF);
        int p2 = rowPtr[d4.z] + off[(size_t)(((unsigned)r4.z) >> 24) * Nn + d4.z] + (r4.z & 0x00FFFFFF);
        int p3 = rowPtr[d4.w] + off[(size_t)(((unsigned)r4.w) >> 24) * Nn + d4.w] + (r4.w & 0x00FFFFFF);
        int2 e0; e0.x = s4.x; e0.y = __float_as_int(dinv[s4.x] * dinv[d4.x]);
        int2 e1; e1.x = s4.y; e1.y = __float_as_int(dinv[s4.y] * dinv[d4.y]);
        int2 e2; e2.x = s4.z; e2.y = __float_as_int(dinv[s4.z] * dinv[d4.z]);
        int2 e3; e3.x = s4.w; e3.y = __float_as_int(dinv[s4.w] * dinv[d4.w]);
        edata[p0] = e0; edata[p1] = e1; edata[p2] = e2; edata[p3] = e3;
    } else {
        for (int j = 0; j < 4; ++j) {
            int e = i + j;
            if (e >= E) break;
            int s = src[e], d = dst[e];
            int r = rank[e];
            int2 p; p.x = s; p.y = __float_as_int(dinv[s] * dinv[d]);
            edata[rowPtr[d] + off[(size_t)(((unsigned)r) >> 24) * Nn + d] + (r & 0x00FFFFFF)] = p;
        }
    }
}

// ------- packed-A GEMM (layer 2, bf16 out) --------------------------------
template <int KSTEPS, int NTILES>
__global__ __launch_bounds__(256) void k_gemm_p(
        const bf16_t* __restrict__ Ap, const bf16_t* __restrict__ Bp,
        bf16_t* __restrict__ C, int M) {
    int wave = (blockIdx.x * blockDim.x + threadIdx.x) >> 6;
    if (wave * 16 >= M) return;
    int lane = threadIdx.x & 63;
    int r16 = lane & 15, quad = lane >> 4;
    const int N = NTILES * 16;
    f32x4 acc[NTILES] = {};
    const bf16_t* apb = Ap + (size_t)wave * (KSTEPS * 512) + lane * 8;
#pragma unroll
    for (int s = 0; s < KSTEPS; ++s) {
        bf16x8 a = *(const bf16x8*)(apb + s * 512);
        const bf16_t* bp = Bp + ((size_t)(s * NTILES) * 64 + lane) * 8;
#pragma unroll
        for (int t = 0; t < NTILES; ++t) {
            bf16x8 b = *(const bf16x8*)(bp + t * 512);
            acc[t] = __builtin_amdgcn_mfma_f32_16x16x32_bf16(a, b, acc[t], 0, 0, 0);
        }
    }
#pragma unroll
    for (int t = 0; t < NTILES; ++t)
#pragma unroll
        for (int r = 0; r < 4; ++r)
            C[(size_t)(wave * 16 + quad * 4 + r) * N + t * 16 + r16] = (bf16_t)acc[t][r];
}

// ------- layer-1 aggregate over fp8 XW1 rows (128B), packed Hp out --------
__global__ __launch_bounds__(256) void k_agg1(
        const int* __restrict__ rowPtr, const int2* __restrict__ edata,
        const unsigned char* __restrict__ XW1, const float* __restrict__ dinv,
        const float* __restrict__ b1, bf16_t* __restrict__ Hp, int n) {
    int wave = (blockIdx.x * blockDim.x + threadIdx.x) >> 6;
    if (wave >= n) return;
    int lane = threadIdx.x & 63;
    int fl = (lane & 15) << 3;   // 8 features (bytes, 1B/feat)
    int h  = lane >> 4;          // parity stream 0..3
    int r0 = rowPtr[wave], r1 = rowPtr[wave + 1];
    // self-term preload (independent, hides under the gather loop)
    float d = dinv[wave], d2 = d * d;
    uint2 us = *(const uint2*)(XW1 + (size_t)wave * 128 + fl);
    float a0[8] = {}, a1[8] = {};
    int k = r0 + h;
    for (; k + 4 < r1; k += 8) {          // 2 independent gathers in flight
        int2 e0 = edata[k], e1 = edata[k + 4];
        float w0 = __int_as_float(e0.y), w1 = __int_as_float(e1.y);
        uint2 u0 = *(const uint2*)(XW1 + (size_t)e0.x * 128 + fl);
        uint2 u1 = *(const uint2*)(XW1 + (size_t)e1.x * 128 + fl);
        fma8_fp8(u0, w0, a0);
        fma8_fp8(u1, w1, a1);
    }
    if (k < r1) {
        int2 e0 = edata[k];
        float w0 = __int_as_float(e0.y);
        uint2 u0 = *(const uint2*)(XW1 + (size_t)e0.x * 128 + fl);
        fma8_fp8(u0, w0, a0);
    }
#pragma unroll
    for (int j = 0; j < 8; ++j) {        // convergent reduction over 4 streams
        a0[j] += a1[j];
        a0[j] += __shfl_xor(a0[j], 16);
        a0[j] += __shfl_xor(a0[j], 32);
    }
    if (h == 0) {
        fma8_fp8(us, d2, a0);            // self term
        bf16x8 hv;
#pragma unroll
        for (int j = 0; j < 8; ++j) {
            float v = a0[j] + b1[fl + j];
            hv[j] = (bf16_t)fmaxf(v, 0.f);
        }
        int q = lane & 15;
        size_t off2 = (((size_t)(wave >> 4) * 4 + (q >> 2)) * 64
                       + (wave & 15) + 16 * (q & 3)) * 8;
        *(bf16x8*)(Hp + off2) = hv;
    }
}

// ------- layer-2 aggregate + log_softmax (bf16 XW2) -----------------------
__global__ __launch_bounds__(256) void k_agg2(
        const int* __restrict__ rowPtr, const int2* __restrict__ edata,
        const bf16_t* __restrict__ XW2, const float* __restrict__ dinv,
        const float* __restrict__ b2, float* __restrict__ out, int n) {
    int wave = (blockIdx.x * blockDim.x + threadIdx.x) >> 6;
    if (wave >= n) return;
    int lane = threadIdx.x & 63;
    int g = lane & 15;           // class pair: {2g, 2g+1}
    int h = lane >> 4;           // stream 0..3
    int r0 = rowPtr[wave], r1 = rowPtr[wave + 1];
    // self-term preload
    float d = dinv[wave], d2 = d * d;
    unsigned ps = *(const unsigned*)(XW2 + ((size_t)wave << 5) + 2 * g);
    float2 bb = *(const float2*)(b2 + 2 * g);
    float a00 = 0.f, a01 = 0.f, a10 = 0.f, a11 = 0.f;
    int k = r0 + h;
    for (; k + 4 < r1; k += 8) {
        int2 e0 = edata[k], e1 = edata[k + 4];
        float w0 = __int_as_float(e0.y), w1 = __int_as_float(e1.y);
        unsigned p0 = *(const unsigned*)(XW2 + ((size_t)e0.x << 5) + 2 * g);
        unsigned p1 = *(const unsigned*)(XW2 + ((size_t)e1.x << 5) + 2 * g);
        a00 += __int_as_float(p0 << 16) * w0;
        a01 += __int_as_float(p0 & 0xffff0000u) * w0;
        a10 += __int_as_float(p1 << 16) * w1;
        a11 += __int_as_float(p1 & 0xffff0000u) * w1;
    }
    if (k < r1) {
        int2 e0 = edata[k];
        float w0 = __int_as_float(e0.y);
        unsigned p0 = *(const unsigned*)(XW2 + ((size_t)e0.x << 5) + 2 * g);
        a00 += __int_as_float(p0 << 16) * w0;
        a01 += __int_as_float(p0 & 0xffff0000u) * w0;
    }
    float v0 = a00 + a10, v1 = a01 + a11;
    v0 += __shfl_xor(v0, 16); v0 += __shfl_xor(v0, 32);   // combine 4 streams
    v1 += __shfl_xor(v1, 16); v1 += __shfl_xor(v1, 32);
    v0 += __int_as_float(ps << 16) * d2 + bb.x;
    v1 += __int_as_float(ps & 0xffff0000u) * d2 + bb.y;
    float mx = fmaxf(v0, v1);
#pragma unroll
    for (int m = 8; m >= 1; m >>= 1) mx = fmaxf(mx, __shfl_xor(mx, m));
    float s = __expf(v0 - mx) + __expf(v1 - mx);
#pragma unroll
    for (int m = 8; m >= 1; m >>= 1) s += __shfl_xor(s, m);
    if (h == 0) {
        float ls = __logf(s);
        float2 o; o.x = v0 - mx - ls; o.y = v1 - mx - ls;
        *(float2*)(out + ((size_t)wave << 5) + 2 * g) = o;
    }
}

extern "C" void kernel_launch(void* const* d_in, const int* in_sizes, int n_in,
                              void* d_out, int out_size, void* d_ws, size_t ws_size,
                              hipStream_t stream) {
    const float* feat = (const float*)d_in[0];
    const int*   eidx = (const int*)d_in[1];
    const float* W1   = (const float*)d_in[2];
    const float* b1   = (const float*)d_in[3];
    const float* W2   = (const float*)d_in[4];
    const float* b2   = (const float*)d_in[5];
    float* out = (float*)d_out;

    const int FIN = 256, HID = 128, NCLS = 32;
    const int N = in_sizes[0] / FIN;   // 100000
    const int E = in_sizes[1] / 2;     // 800000
    const int* src = eidx;
    const int* dst = eidx + E;

    // workspace carve-up (256B aligned)
    char* ws = (char*)d_ws;
    size_t o = 0;
    auto alloc = [&](size_t bytes) -> void* {
        void* p = ws + o;
        o = (o + bytes + 255) & ~(size_t)255;
        return p;
    };
    int*    degS   = (int*)   alloc((size_t)SLICES * N * 4);  // 6.4 MB slice planes
    int*    offA   = (int*)   alloc((size_t)SLICES * N * 4);  // 6.4 MB per-slice offsets
    int*    degTot = (int*)   alloc((size_t)N * 4);
    int*    rank   = (int*)   alloc((size_t)E * 4);           // 3.2 MB tagged ranks
    float*  dinv   = (float*) alloc((size_t)N * 4);
    int*    rowPtr = (int*)   alloc((size_t)(N + 1) * 4);
    int*    bsum   = (int*)   alloc(256 * 4);
    bf16_t* Bp1    = (bf16_t*)alloc((size_t)(FIN / 32) * (HID / 16) * 512 * 2);
    bf16_t* Bp2    = (bf16_t*)alloc((size_t)(HID / 32) * (NCLS / 16) * 512 * 2);
    int2*   edata  = (int2*)  alloc((size_t)E * 8);           // 6.4 MB
    unsigned char* XW1 = (unsigned char*)alloc((size_t)N * HID);  // 12.8 MB fp8
    bf16_t* Hp     = (bf16_t*)alloc((size_t)N * HID * 2);     // 25.6 MB packed H
    bf16_t* XW2    = (bf16_t*)XW1;  // alias: XW1 dead after k_agg1 (6.4 <= 12.8 MB)

    const int T = 256;
    const int NB = (N + 1023) >> 10;                 // 98 scan blocks (<=256)
    const int DEGB  = RANGES * SLICES;               // 512 LDS-histogram blocks
    const int GEMMB = (((N + 15) / 16) * 64 + T - 1) / T;   // 1563
    const int PACKB = (32768 + 4096) / 256;          // 144

    k_prep      <<<PACKB, T, 0, stream>>>(W1, Bp1, W2, Bp2);
    k_front<8, 8><<<DEGB + GEMMB, T, 0, stream>>>(
        feat, Bp1, XW1, N, dst, degS, rank, N, E, DEGB);
    k_dinv_scan1<<<NB, T, 0, stream>>>(degS, degTot, offA, dinv, bsum, N);
    k_scan3f    <<<NB, T, 0, stream>>>(degTot, bsum, NB, rowPtr, N);
    k_scatter   <<<(E + 1023) / 1024, T, 0, stream>>>(
        src, dst, rank, rowPtr, offA, dinv, edata, N, E);
    k_agg1<<<(N * 64 + T - 1) / T, T, 0, stream>>>(rowPtr, edata, XW1, dinv, b1, Hp, N);
    // layer 2: XW2 = bf16(Hp @ W2), A packed
    {
        int waves = (N + 15) / 16;
        k_gemm_p<4, 2><<<(waves * 64 + T - 1) / T, T, 0, stream>>>(Hp, Bp2, XW2, N);
    }
    k_agg2<<<(N * 64 + T - 1) / T, T, 0, stream>>>(rowPtr, edata, XW2, dinv, b2, out, N);
}